// Round 11
// baseline (134.678 us; speedup 1.0000x reference)
//
#include <hip/hip_runtime.h>
#include <math.h>

#define NQ    14
#define DIM   16384
#define DEPTH 4

typedef __attribute__((ext_vector_type(2))) float f2;
typedef __attribute__((ext_vector_type(4))) float f4;

__device__ __forceinline__ f2 cmul(f2 a, f2 b) {
    return (f2){a.x*b.x - a.y*b.y, a.x*b.y + a.y*b.x};
}

// wave-uniform value -> SGPR
__device__ __forceinline__ float rfl(float x) {
    return __int_as_float(__builtin_amdgcn_readfirstlane(__float_as_int(x)));
}

template<int CTRL>
__device__ __forceinline__ float dpp1(float v) {
    return __int_as_float(__builtin_amdgcn_update_dpp(
        0, __float_as_int(v), CTRL, 0xF, 0xF, true));
}
template<int XB> __device__ __forceinline__ float lx(float v);
template<> __device__ __forceinline__ float lx<1>(float v) { return dpp1<0xB1>(v); }   // quad_perm [1,0,3,2]
template<> __device__ __forceinline__ float lx<2>(float v) { return dpp1<0x4E>(v); }   // quad_perm [2,3,0,1]
template<> __device__ __forceinline__ float lx<8>(float v) { return dpp1<0x128>(v); }  // row_ror:8 == xor8

// ---------------- register-resident state, two views (verified r10) --------
// n = t&63, w = t>>6. Qubit q <-> amplitude bit e[13-q].
// View A: e13..e10 = l3..l0 (q0-3 reg); e9..e4 = n5..n0; e3..e0 = w.
//   A gates: q0-3 reg, q6 (n3, xor8), q8 (n1, xor2), q9 (n0, xor1).
// View B: e3..e0 = l3..l0 (q10-13 reg); e13..e10 = w;
//         e9=n3, e8=n1, e7=n5, e6=n0, e5=n4, e4=n2.
//   B gates: q10-13 reg, q4 (n3, xor8), q5 (n1, xor2), q7 (n0, xor1).
// Remap LDS layout: L(e) = e[7:4] | (e[9:8]<<4) | (e[3:0]<<6) | (e[13:10]<<10)
//   A-side: t + (l<<10);  B-side: baseB + (l<<6). Conflict-free both sides.
//
// Gate coefficients are wave-uniform: loaded from LDS 1 gate ahead (2x
// ds_read_b128 prefetch) and moved to SGPRs via readfirstlane -> inner loops
// are pure v_fma (one SGPR operand each), no lgkm waits in the chain. This
// attacks r10's diagnosis: VALU issue is ~23us (= measured VALUBusy), the
// other ~22us was per-gate lgkm stalls hitting all 4 barrier-synced waves
// at once.

struct GS {
    float u00r,u00i,u01r,u01i,u10r,u10i,u11r,u11i;
};
__device__ __forceinline__ GS rflg(f4 va, f4 vb) {
    GS g;
    g.u00r = rfl(va.x); g.u00i = rfl(va.y);
    g.u01r = rfl(va.z); g.u01i = rfl(va.w);
    g.u10r = rfl(vb.x); g.u10i = rfl(vb.y);
    g.u11r = rfl(vb.z); g.u11i = rfl(vb.w);
    return g;
}

// Register-qubit gate: butterfly across amp-index bit MASK. 16 fma/pair.
template<int MASK>
__device__ __forceinline__ void reg_gate_s(float* ar, float* ai, const GS g) {
    #pragma unroll
    for (int l = 0; l < 16; ++l) {
        if (l & MASK) continue;
        const int j = l | MASK;
        float xr = ar[l], xi = ai[l], yr = ar[j], yi = ai[j];
        ar[l] = g.u00r*xr - g.u00i*xi + g.u01r*yr - g.u01i*yi;
        ai[l] = g.u00r*xi + g.u00i*xr + g.u01r*yi + g.u01i*yr;
        ar[j] = g.u10r*xr - g.u10i*xi + g.u11r*yr - g.u11i*yi;
        ai[j] = g.u10r*xi + g.u10i*xr + g.u11r*yi + g.u11i*yr;
    }
}

// Lane-qubit gate: DPP exchange; lane computes its own half.
template<int XB>
__device__ __forceinline__ void lane_gate_s(float* ar, float* ai, const GS g, int t) {
    const bool hi = (t & XB) != 0;
    const float c1r = hi ? g.u11r : g.u00r;
    const float c1i = hi ? g.u11i : g.u00i;
    const float c2r = hi ? g.u10r : g.u01r;
    const float c2i = hi ? g.u10i : g.u01i;
    #pragma unroll
    for (int l = 0; l < 16; ++l) {
        float pr = lx<XB>(ar[l]);
        float pi = lx<XB>(ai[l]);
        float xr = ar[l], xi = ai[l];
        ar[l] = c1r*xr - c1i*xi + c2r*pr - c2i*pi;
        ai[l] = c1r*xi + c1i*xr + c2r*pi + c2i*pr;
    }
}

// CZ sign in view A: e = (l<<10)|(n<<4)|w.  (verified r10)
__device__ __forceinline__ void cz_A(float* ar, float* ai, int t) {
    const int n = t & 63, w = t >> 6;
    const int pT = (__popc(w & (w >> 1)) + __popc(n & (n >> 1)) + ((n & 1) & (w >> 3))) & 1;
    const float F0 = pT ? -1.f : 1.f;
    const float F1 = (pT ^ ((n >> 5) & 1)) ? -1.f : 1.f;
    #pragma unroll
    for (int l = 0; l < 16; ++l) {
        float s = (l & 1) ? F1 : F0;                 // cross term l0 & n5
        if (__popc(l & (l >> 1)) & 1) s = -s;        // compile-time per l
        ar[l] *= s; ai[l] *= s;
    }
}

// CZ sign in view B: e9=n3,e8=n1,e7=n5,e6=n0,e5=n4,e4=n2.  (verified r10)
__device__ __forceinline__ void cz_B(float* ar, float* ai, int t) {
    const int n = t & 63, w = t >> 6;
    const int n0 = n & 1, n1 = (n >> 1) & 1, n2 = (n >> 2) & 1;
    const int n3 = (n >> 3) & 1, n4 = (n >> 4) & 1, n5 = (n >> 5) & 1;
    const int pT = ((n2 & n4) ^ (n4 & n0) ^ (n0 & n5) ^ (n5 & n1) ^ (n1 & n3)
                    ^ (n3 & (w & 1)) ^ (__popc(w & (w >> 1)) & 1));
    const float F0 = pT ? -1.f : 1.f;
    const float F1 = (pT ^ n2) ? -1.f : 1.f;
    #pragma unroll
    for (int l = 0; l < 16; ++l) {
        float s = (l & 8) ? F1 : F0;                 // cross term l3 & n2
        if (__popc(l & (l >> 1)) & 1) s = -s;        // compile-time per l
        ar[l] *= s; ai[l] *= s;
    }
}

__global__ __launch_bounds__(1024)
void qlg_kernel(const float* __restrict__ cond,
                const float* __restrict__ Wenc,
                const float* __restrict__ benc,
                const float* __restrict__ wts,
                float* __restrict__ out)
{
    __shared__ f2 st[DIM];                  // 128 KB remap buffer (L-layout)
    __shared__ f4 gatesL[DEPTH][NQ][2];     // per gate: {u00,u01},{u10,u11}
    __shared__ f2 qv[NQ][2];
    __shared__ f2 Phi[128];
    __shared__ f2 Plo[128];
    __shared__ float embS[NQ];
    __shared__ float wred[16][NQ];
    __shared__ float lat[NQ];

    const int b = blockIdx.x;
    const int t = threadIdx.x;
    const int n = t & 63, w = t >> 6;
    const int bB = (w << 10)
                 | (((n >> 3) & 1) << 5) | (((n >> 1) & 1) << 4)
                 | (((n >> 5) & 1) << 3) | ((n & 1) << 2)
                 | (((n >> 4) & 1) << 1) | ((n >> 2) & 1);

    // ---- stage 1: embedding (SiLU) + gate matrices ----
    if (t < NQ) {
        float s = benc[t];
        #pragma unroll
        for (int k = 0; k < NQ; ++k) s += cond[b*NQ + k] * Wenc[t*NQ + k];
        embS[t] = s / (1.0f + __expf(-s));
    }
    if (t >= 64 && t < 64 + DEPTH*NQ) {
        const int gi = t - 64;
        const int d = gi / NQ, ww = gi % NQ;
        const float p0 = wts[(d*NQ + ww)*3 + 0];
        const float p1 = wts[(d*NQ + ww)*3 + 1];
        const float p2 = wts[(d*NQ + ww)*3 + 2];
        float s0, c0, s1, c1, s2, c2;
        sincosf(0.5f*p0, &s0, &c0);
        sincosf(0.5f*p1, &s1, &c1);
        sincosf(0.5f*p2, &s2, &c2);
        // U = RY(p2) * RX(p1) * RZ(p0)
        f2 e0  = (f2){c0, -s0};
        f2 e0c = (f2){c0,  s0};
        f2 is1 = (f2){0.f, -s1};
        f2 m00 = c1 * e0;
        f2 m01 = cmul(is1, e0c);
        f2 m10 = cmul(is1, e0);
        f2 m11 = c1 * e0c;
        f2 u00 = c2*m00 - s2*m10;
        f2 u01 = c2*m01 - s2*m11;
        f2 u10 = s2*m00 + c2*m10;
        f2 u11 = s2*m01 + c2*m11;
        gatesL[d][ww][0] = (f4){u00.x, u00.y, u01.x, u01.y};
        gatesL[d][ww][1] = (f4){u10.x, u10.y, u11.x, u11.y};
    }
    __syncthreads();

    // ---- stage 2: per-wire 2-vectors after encoding + layer 0 ----
    if (t < NQ) {
        float v = embS[t];
        float s, c;
        sincosf(0.5f*v, &s, &c);
        f2 a0 = (f2){c*c,  s*s};
        f2 a1 = (f2){s*c, -s*c};
        f4 va = gatesL[0][t][0], vb = gatesL[0][t][1];
        f2 u00 = (f2){va.x, va.y}, u01 = (f2){va.z, va.w};
        f2 u10 = (f2){vb.x, vb.y}, u11 = (f2){vb.z, vb.w};
        qv[t][0] = cmul(u00, a0) + cmul(u01, a1);
        qv[t][1] = cmul(u10, a0) + cmul(u11, a1);
    }
    __syncthreads();

    // ---- stage 3: partial-product tables ----
    if (t < 128) {
        f2 p = qv[0][(t >> 6) & 1];
        #pragma unroll
        for (int ww = 1; ww <= 6; ++ww) p = cmul(p, qv[ww][(t >> (6 - ww)) & 1]);
        Phi[t] = p;
    } else if (t < 256) {
        const int j = t - 128;
        f2 p = qv[7][(j >> 6) & 1];
        #pragma unroll
        for (int ww = 8; ww <= 13; ++ww) p = cmul(p, qv[ww][(j >> (13 - ww)) & 1]);
        Plo[j] = p;
    }
    __syncthreads();

    // ---- stage 4: build product state IN REGISTERS (view A), CZ0 fused ----
    float ar[16], ai[16];
    {
        f2 plo = Plo[((n & 7) << 4) | w];
        #pragma unroll
        for (int l = 0; l < 16; ++l) {
            f2 ph = Phi[(l << 3) | (n >> 3)];
            ar[l] = ph.x*plo.x - ph.y*plo.y;
            ai[l] = ph.x*plo.y + ph.y*plo.x;
        }
        cz_A(ar, ai, t);
    }

    f4 va, vb, na, nb;
    #define PREF(A_, B_, d_, q_) { A_ = gatesL[d_][q_][0]; B_ = gatesL[d_][q_][1]; }

    // ---- segment 1 (view A): layer-1 q0-3 reg, q6/q8/q9 DPP ----
    PREF(va, vb, 1, 0);
    PREF(na, nb, 1, 1); { GS G = rflg(va, vb); reg_gate_s<8>(ar, ai, G); }
    PREF(va, vb, 1, 2); { GS G = rflg(na, nb); reg_gate_s<4>(ar, ai, G); }
    PREF(na, nb, 1, 3); { GS G = rflg(va, vb); reg_gate_s<2>(ar, ai, G); }
    PREF(va, vb, 1, 6); { GS G = rflg(na, nb); reg_gate_s<1>(ar, ai, G); }
    PREF(na, nb, 1, 8); { GS G = rflg(va, vb); lane_gate_s<8>(ar, ai, G, t); }
    PREF(va, vb, 1, 9); { GS G = rflg(na, nb); lane_gate_s<2>(ar, ai, G, t); }
                        { GS G = rflg(va, vb); lane_gate_s<1>(ar, ai, G, t); }

    // ---- remap 1: A -> B ----
    #pragma unroll
    for (int l = 0; l < 16; ++l) st[t + (l << 10)] = (f2){ar[l], ai[l]};
    __syncthreads();
    #pragma unroll
    for (int l = 0; l < 16; ++l) { f2 v = st[bB + (l << 6)]; ar[l] = v.x; ai[l] = v.y; }

    // ---- segment 2 (view B): layer-1 B-part + CZ1 + layer-2 B-part ----
    PREF(va, vb, 1, 10);
    PREF(na, nb, 1, 11); { GS G = rflg(va, vb); reg_gate_s<8>(ar, ai, G); }
    PREF(va, vb, 1, 12); { GS G = rflg(na, nb); reg_gate_s<4>(ar, ai, G); }
    PREF(na, nb, 1, 13); { GS G = rflg(va, vb); reg_gate_s<2>(ar, ai, G); }
    PREF(va, vb, 1, 4);  { GS G = rflg(na, nb); reg_gate_s<1>(ar, ai, G); }
    PREF(na, nb, 1, 5);  { GS G = rflg(va, vb); lane_gate_s<8>(ar, ai, G, t); }
    PREF(va, vb, 1, 7);  { GS G = rflg(na, nb); lane_gate_s<2>(ar, ai, G, t); }
    PREF(na, nb, 2, 10); { GS G = rflg(va, vb); lane_gate_s<1>(ar, ai, G, t); }
    cz_B(ar, ai, t);
    PREF(va, vb, 2, 11); { GS G = rflg(na, nb); reg_gate_s<8>(ar, ai, G); }
    PREF(na, nb, 2, 12); { GS G = rflg(va, vb); reg_gate_s<4>(ar, ai, G); }
    PREF(va, vb, 2, 13); { GS G = rflg(na, nb); reg_gate_s<2>(ar, ai, G); }
    PREF(na, nb, 2, 4);  { GS G = rflg(va, vb); reg_gate_s<1>(ar, ai, G); }
    PREF(va, vb, 2, 5);  { GS G = rflg(na, nb); lane_gate_s<8>(ar, ai, G, t); }
    PREF(na, nb, 2, 7);  { GS G = rflg(va, vb); lane_gate_s<2>(ar, ai, G, t); }
                         { GS G = rflg(na, nb); lane_gate_s<1>(ar, ai, G, t); }

    // ---- remap 2: B -> A ----
    // NOTE: no barrier before the stores — each thread overwrites exactly the
    // addresses it itself read in remap 1 (per-thread address sets are equal),
    // so there is no cross-thread hazard.
    #pragma unroll
    for (int l = 0; l < 16; ++l) st[bB + (l << 6)] = (f2){ar[l], ai[l]};
    __syncthreads();
    #pragma unroll
    for (int l = 0; l < 16; ++l) { f2 v = st[t + (l << 10)]; ar[l] = v.x; ai[l] = v.y; }

    // ---- segment 3 (view A): layer-2 A-part + CZ2 + layer-3 A-part ----
    PREF(va, vb, 2, 0);
    PREF(na, nb, 2, 1); { GS G = rflg(va, vb); reg_gate_s<8>(ar, ai, G); }
    PREF(va, vb, 2, 2); { GS G = rflg(na, nb); reg_gate_s<4>(ar, ai, G); }
    PREF(na, nb, 2, 3); { GS G = rflg(va, vb); reg_gate_s<2>(ar, ai, G); }
    PREF(va, vb, 2, 6); { GS G = rflg(na, nb); reg_gate_s<1>(ar, ai, G); }
    PREF(na, nb, 2, 8); { GS G = rflg(va, vb); lane_gate_s<8>(ar, ai, G, t); }
    PREF(va, vb, 2, 9); { GS G = rflg(na, nb); lane_gate_s<2>(ar, ai, G, t); }
    PREF(na, nb, 3, 0); { GS G = rflg(va, vb); lane_gate_s<1>(ar, ai, G, t); }
    cz_A(ar, ai, t);
    PREF(va, vb, 3, 1); { GS G = rflg(na, nb); reg_gate_s<8>(ar, ai, G); }
    PREF(na, nb, 3, 2); { GS G = rflg(va, vb); reg_gate_s<4>(ar, ai, G); }
    PREF(va, vb, 3, 3); { GS G = rflg(na, nb); reg_gate_s<2>(ar, ai, G); }
    PREF(na, nb, 3, 6); { GS G = rflg(va, vb); reg_gate_s<1>(ar, ai, G); }
    PREF(va, vb, 3, 8); { GS G = rflg(na, nb); lane_gate_s<8>(ar, ai, G, t); }
    PREF(na, nb, 3, 9); { GS G = rflg(va, vb); lane_gate_s<2>(ar, ai, G, t); }
                        { GS G = rflg(na, nb); lane_gate_s<1>(ar, ai, G, t); }

    // ---- remap 3: A -> B ----  (same per-thread address-set argument)
    #pragma unroll
    for (int l = 0; l < 16; ++l) st[t + (l << 10)] = (f2){ar[l], ai[l]};
    __syncthreads();
    #pragma unroll
    for (int l = 0; l < 16; ++l) { f2 v = st[bB + (l << 6)]; ar[l] = v.x; ai[l] = v.y; }

    // ---- segment 4 (view B): layer-3 B-part + fused probability reduction ----
    float SU, Q10, Q11, Q12, Q13;
    {
        PREF(va, vb, 3, 10);
        PREF(na, nb, 3, 11); { GS G = rflg(va, vb); reg_gate_s<8>(ar, ai, G); }
        PREF(va, vb, 3, 12); { GS G = rflg(na, nb); reg_gate_s<4>(ar, ai, G); }
        PREF(na, nb, 3, 13); { GS G = rflg(va, vb); reg_gate_s<2>(ar, ai, G); }
        PREF(va, vb, 3, 4);  { GS G = rflg(na, nb); reg_gate_s<1>(ar, ai, G); }
        PREF(na, nb, 3, 5);  { GS G = rflg(va, vb); lane_gate_s<8>(ar, ai, G, t); }
        PREF(va, vb, 3, 7);  { GS G = rflg(na, nb); lane_gate_s<2>(ar, ai, G, t); }
                             { GS G = rflg(va, vb); lane_gate_s<1>(ar, ai, G, t); }
        // (CZ after layer 3 dropped: |psi|^2 invariant)
        SU = Q10 = Q11 = Q12 = Q13 = 0.f;
        #pragma unroll
        for (int l = 0; l < 16; ++l) {
            float p = ar[l]*ar[l] + ai[l]*ai[l];
            SU  += p;
            Q10 += (l & 8) ? -p : p;    // q10 <-> e3 = l3
            Q11 += (l & 4) ? -p : p;
            Q12 += (l & 2) ? -p : p;
            Q13 += (l & 1) ? -p : p;
        }
    }

    // ---- stage 6: reduce to 14 expectations, layernorm ----
    // View-B sign bit (thread-uniform) for wire ww in 0..9:
    // q0:t9 q1:t8 q2:t7 q3:t6 q4:t3 q5:t1 q6:t5 q7:t0 q8:t4 q9:t2.
    {
        const int lane = t & 63, wv = t >> 6;
        const int sbit[10] = {9, 8, 7, 6, 3, 1, 5, 0, 4, 2};
        #pragma unroll
        for (int ww = 0; ww < NQ; ++ww) {
            float v;
            if      (ww == 10) v = Q10;
            else if (ww == 11) v = Q11;
            else if (ww == 12) v = Q12;
            else if (ww == 13) v = Q13;
            else               v = ((t >> sbit[ww]) & 1) ? -SU : SU;
            #pragma unroll
            for (int off = 32; off > 0; off >>= 1) v += __shfl_down(v, off, 64);
            if (lane == 0) wred[wv][ww] = v;
        }
    }
    __syncthreads();
    if (t < NQ) {
        float s = 0.f;
        #pragma unroll
        for (int k = 0; k < 16; ++k) s += wred[k][t];
        lat[t] = s;
    }
    __syncthreads();
    if (t < NQ) {
        float mu = 0.f;
        #pragma unroll
        for (int k = 0; k < NQ; ++k) mu += lat[k];
        mu *= (1.0f / NQ);
        float var = 0.f;
        #pragma unroll
        for (int k = 0; k < NQ; ++k) { float dv = lat[k] - mu; var += dv*dv; }
        var *= (1.0f / NQ);
        out[b*NQ + t] = (lat[t] - mu) * rsqrtf(var + 1e-5f);
    }
}

extern "C" void kernel_launch(void* const* d_in, const int* in_sizes, int n_in,
                              void* d_out, int out_size, void* d_ws, size_t ws_size,
                              hipStream_t stream)
{
    (void)n_in; (void)d_ws; (void)ws_size; (void)out_size;
    const float* cond = (const float*)d_in[0];
    const float* Wenc = (const float*)d_in[1];
    const float* benc = (const float*)d_in[2];
    const float* wts  = (const float*)d_in[3];
    float* out = (float*)d_out;
    const int B = in_sizes[0] / NQ;   // 256
    qlg_kernel<<<dim3(B), dim3(1024), 0, stream>>>(cond, Wenc, benc, wts, out);
}

// Round 12
// 98.995 us; speedup vs baseline: 1.3604x; 1.3604x over previous
//
#include <hip/hip_runtime.h>
#include <math.h>

#define NQ    14
#define DIM   16384
#define DEPTH 4

// Packed-fp32 complex: f2 = (re, im) -> v_pk_fma_f32 (2 FLOP/instr; same FLOP
// rate as scalar but HALF the instruction stream — r11 proved scalar doubles
// issue time).
typedef __attribute__((ext_vector_type(2))) float f2;
typedef __attribute__((ext_vector_type(4))) float f4;

__device__ __forceinline__ f2 cmul(f2 a, f2 b) {
    return (f2){a.x*b.x - a.y*b.y, a.x*b.y + a.y*b.x};
}
// out = u*x + v*y (complex), pre-swapped forms us=(-u.i,u.r): 1 pk_mul + 3 pk_fma
__device__ __forceinline__ f2 cmac2(f2 x, f2 u, f2 us, f2 y, f2 v, f2 vs) {
    f2 r = x.xx * u;
    r += x.yy * us;
    r += y.xx * v;
    r += y.yy * vs;
    return r;
}

// ---------------- register-resident state, two views (HW-verified r10) -----
// n = t&63, w = t>>6. Qubit q <-> amplitude bit e[13-q].
// View A: e13..e10 = l3..l0 (q0-3 reg); e9..e4 = n5..n0; e3..e0 = w.
//   A gates: q0-3 reg(8,4,2,1), q6 (xor8), q8 (xor2), q9 (xor1).
// View B: e3..e0 = l3..l0 (q10-13 reg); e13..e10 = w;
//         e9=n3, e8=n1, e7=n5, e6=n0, e5=n4, e4=n2.
//   B gates: q10-13 reg(8,4,2,1), q4 (xor8), q5 (xor2), q7 (xor1).
// Both gate sequences have IDENTICAL code structure -> one loop body over a
// schedule table. This shrinks the hot code ~5x: rounds 5-10 were fully
// unrolled (~40 KB), streaming I-fetch from L2 pinned VALU duty at ~50%.
//
// Remap LDS layout: L(e) = e[7:4] | (e[9:8]<<4) | (e[3:0]<<6) | (e[13:10]<<10)
//   A-side: t + (l<<10);  B-side: baseB + (l<<6). Conflict-free both sides.
//   One barrier per remap (store set == own previous read set; verified r11).

// ---- cross-lane exchanges (all DPP = pure VALU) ----
template<int CTRL>
__device__ __forceinline__ f2 dpp2(f2 v) {
    union U { f2 f; int i[2]; } u, r;
    u.f = v;
    r.i[0] = __builtin_amdgcn_update_dpp(0, u.i[0], CTRL, 0xF, 0xF, true);
    r.i[1] = __builtin_amdgcn_update_dpp(0, u.i[1], CTRL, 0xF, 0xF, true);
    return r.f;
}
template<int XB> __device__ __forceinline__ f2 lxchg(f2 v);
template<> __device__ __forceinline__ f2 lxchg<1>(f2 v) { return dpp2<0xB1>(v); }   // quad_perm [1,0,3,2]
template<> __device__ __forceinline__ f2 lxchg<2>(f2 v) { return dpp2<0x4E>(v); }   // quad_perm [2,3,0,1]
template<> __device__ __forceinline__ f2 lxchg<8>(f2 v) { return dpp2<0x128>(v); }  // row_ror:8 == xor8

// Register-qubit gate over 16 amps: butterfly across amp-index bit MASK.
template<int MASK>
__device__ __forceinline__ void reg_gate(f2 a[16], const f4* G) {
    f4 g0 = G[0], g1 = G[1], g2 = G[2], g3 = G[3];
    #pragma unroll
    for (int l = 0; l < 16; ++l) {
        if (l & MASK) continue;
        const int j = l | MASK;
        f2 x = a[l], y = a[j];
        a[l] = cmac2(x, g0.xy, g0.zw, y, g1.xy, g1.zw);
        a[j] = cmac2(x, g2.xy, g2.zw, y, g3.xy, g3.zw);
    }
}

// Lane-qubit gate: DPP exchange; each lane computes its own half.
// lo lane: rows 0,1 = (u00,u01); hi lane: rows 3,2 = (u11,u10).
template<int XB>
__device__ __forceinline__ void lane_gate(f2 a[16], const f4* G, int t) {
    const bool hi = (t & XB) != 0;
    f4 c1 = G[hi ? 3 : 0];
    f4 c2 = G[hi ? 2 : 1];
    #pragma unroll
    for (int l = 0; l < 16; ++l) {
        f2 p = lxchg<XB>(a[l]);
        a[l] = cmac2(a[l], c1.xy, c1.zw, p, c2.xy, c2.zw);
    }
}

// CZ sign in view A: e = (l<<10)|(n<<4)|w.  (HW-verified r10)
__device__ __forceinline__ void cz_A(f2 a[16], int t) {
    const int n = t & 63, w = t >> 6;
    const int pT = (__popc(w & (w >> 1)) + __popc(n & (n >> 1)) + ((n & 1) & (w >> 3))) & 1;
    const float F0 = pT ? -1.f : 1.f;
    const float F1 = (pT ^ ((n >> 5) & 1)) ? -1.f : 1.f;
    #pragma unroll
    for (int l = 0; l < 16; ++l) {
        float s = (l & 1) ? F1 : F0;                 // cross term l0 & n5
        if (__popc(l & (l >> 1)) & 1) s = -s;        // compile-time per l
        a[l] *= s;
    }
}

// CZ sign in view B: e9=n3,e8=n1,e7=n5,e6=n0,e5=n4,e4=n2.  (HW-verified r10)
__device__ __forceinline__ void cz_B(f2 a[16], int t) {
    const int n = t & 63, w = t >> 6;
    const int n0 = n & 1, n1 = (n >> 1) & 1, n2 = (n >> 2) & 1;
    const int n3 = (n >> 3) & 1, n4 = (n >> 4) & 1, n5 = (n >> 5) & 1;
    const int pT = ((n2 & n4) ^ (n4 & n0) ^ (n0 & n5) ^ (n5 & n1) ^ (n1 & n3)
                    ^ (n3 & (w & 1)) ^ (__popc(w & (w >> 1)) & 1));
    const float F0 = pT ? -1.f : 1.f;
    const float F1 = (pT ^ n2) ? -1.f : 1.f;
    #pragma unroll
    for (int l = 0; l < 16; ++l) {
        float s = (l & 8) ? F1 : F0;                 // cross term l3 & n2
        if (__popc(l & (l >> 1)) & 1) s = -s;        // compile-time per l
        a[l] *= s;
    }
}

__global__ __launch_bounds__(1024)
void qlg_kernel(const float* __restrict__ cond,
                const float* __restrict__ Wenc,
                const float* __restrict__ benc,
                const float* __restrict__ wts,
                float* __restrict__ out)
{
    __shared__ f2 st[DIM];                  // 128 KB remap buffer (L-layout)
    __shared__ f4 gtab[6][7][4];            // schedule-ordered gate table
    __shared__ f4 gates0[NQ][2];            // layer-0 gates (for stage 2 only)
    __shared__ f2 qv[NQ][2];
    __shared__ f2 Phi[128];
    __shared__ f2 Plo[128];
    __shared__ float embS[NQ];
    __shared__ float wred[16][NQ];
    __shared__ float lat[NQ];

    const int b = blockIdx.x;
    const int t = threadIdx.x;
    const int n = t & 63, w = t >> 6;
    const int bB = (w << 10)
                 | (((n >> 3) & 1) << 5) | (((n >> 1) & 1) << 4)
                 | (((n >> 5) & 1) << 3) | ((n & 1) << 2)
                 | (((n >> 4) & 1) << 1) | ((n >> 2) & 1);

    // ---- stage 1: embedding (SiLU) + gate matrices into the schedule ----
    if (t < NQ) {
        float s = benc[t];
        #pragma unroll
        for (int k = 0; k < NQ; ++k) s += cond[b*NQ + k] * Wenc[t*NQ + k];
        embS[t] = s / (1.0f + __expf(-s));
    }
    if (t >= 64 && t < 64 + DEPTH*NQ) {
        const int gi = t - 64;
        const int d = gi / NQ, ww = gi % NQ;
        const float p0 = wts[(d*NQ + ww)*3 + 0];
        const float p1 = wts[(d*NQ + ww)*3 + 1];
        const float p2 = wts[(d*NQ + ww)*3 + 2];
        float s0, c0, s1, c1, s2, c2;
        sincosf(0.5f*p0, &s0, &c0);
        sincosf(0.5f*p1, &s1, &c1);
        sincosf(0.5f*p2, &s2, &c2);
        // U = RY(p2) * RX(p1) * RZ(p0)
        f2 e0  = (f2){c0, -s0};
        f2 e0c = (f2){c0,  s0};
        f2 is1 = (f2){0.f, -s1};
        f2 m00 = c1 * e0;
        f2 m01 = cmul(is1, e0c);
        f2 m10 = cmul(is1, e0);
        f2 m11 = c1 * e0c;
        f2 u00 = c2*m00 - s2*m10;
        f2 u01 = c2*m01 - s2*m11;
        f2 u10 = s2*m00 + c2*m10;
        f2 u11 = s2*m01 + c2*m11;
        if (d == 0) {
            gates0[ww][0] = (f4){u00.x, u00.y, u01.x, u01.y};
            gates0[ww][1] = (f4){u10.x, u10.y, u11.x, u11.y};
        } else {
            // schedule position: half-layers h0..h5 =
            // (1,A),(1,B),(2,B),(2,A),(3,A),(3,B); slot order within a half:
            // A: q0,q1,q2,q3,q6,q8,q9   B: q10,q11,q12,q13,q4,q5,q7
            const bool isA = (ww <= 3) || (ww == 6) || (ww == 8) || (ww == 9);
            int slot;
            if (isA) slot = (ww <= 3) ? ww : (ww == 6 ? 4 : (ww == 8 ? 5 : 6));
            else     slot = (ww >= 10) ? (ww - 10) : (ww == 4 ? 4 : (ww == 5 ? 5 : 6));
            const int h = (d == 1) ? (isA ? 0 : 1)
                        : (d == 2) ? (isA ? 3 : 2)
                                   : (isA ? 4 : 5);
            gtab[h][slot][0] = (f4){u00.x, u00.y, -u00.y, u00.x};
            gtab[h][slot][1] = (f4){u01.x, u01.y, -u01.y, u01.x};
            gtab[h][slot][2] = (f4){u10.x, u10.y, -u10.y, u10.x};
            gtab[h][slot][3] = (f4){u11.x, u11.y, -u11.y, u11.x};
        }
    }
    __syncthreads();

    // ---- stage 2: per-wire 2-vectors after encoding + layer 0 ----
    if (t < NQ) {
        float v = embS[t];
        float s, c;
        sincosf(0.5f*v, &s, &c);
        f2 a0 = (f2){c*c,  s*s};
        f2 a1 = (f2){s*c, -s*c};
        f4 va = gates0[t][0], vb = gates0[t][1];
        f2 u00 = (f2){va.x, va.y}, u01 = (f2){va.z, va.w};
        f2 u10 = (f2){vb.x, vb.y}, u11 = (f2){vb.z, vb.w};
        qv[t][0] = cmul(u00, a0) + cmul(u01, a1);
        qv[t][1] = cmul(u10, a0) + cmul(u11, a1);
    }
    __syncthreads();

    // ---- stage 3: partial-product tables ----
    if (t < 128) {
        f2 p = qv[0][(t >> 6) & 1];
        #pragma unroll
        for (int ww = 1; ww <= 6; ++ww) p = cmul(p, qv[ww][(t >> (6 - ww)) & 1]);
        Phi[t] = p;
    } else if (t < 256) {
        const int j = t - 128;
        f2 p = qv[7][(j >> 6) & 1];
        #pragma unroll
        for (int ww = 8; ww <= 13; ++ww) p = cmul(p, qv[ww][(j >> (13 - ww)) & 1]);
        Plo[j] = p;
    }
    __syncthreads();

    // ---- stage 4: build product state IN REGISTERS (view A), CZ0 fused ----
    f2 a[16];
    {
        f2 plo = Plo[((n & 7) << 4) | w];
        #pragma unroll
        for (int l = 0; l < 16; ++l)
            a[l] = cmul(Phi[(l << 3) | (n >> 3)], plo);
        cz_A(a, t);
    }

    // ---- stage 5: 6 half-layers, one shared body (I-cache resident) ----
    #pragma unroll 1
    for (int h = 0; h < 6; ++h) {
        const f4 (*g)[4] = gtab[h];
        reg_gate<8>(a, g[0]);
        reg_gate<4>(a, g[1]);
        reg_gate<2>(a, g[2]);
        reg_gate<1>(a, g[3]);
        lane_gate<8>(a, g[4], t);
        lane_gate<2>(a, g[5], t);
        lane_gate<1>(a, g[6], t);
        if (h == 1)      cz_B(a, t);   // CZ after layer 1 (view B)
        else if (h == 3) cz_A(a, t);   // CZ after layer 2 (view A)
        if (h == 0 || h == 4) {        // remap A -> B
            #pragma unroll
            for (int l = 0; l < 16; ++l) st[t + (l << 10)] = a[l];
            __syncthreads();
            #pragma unroll
            for (int l = 0; l < 16; ++l) a[l] = st[bB + (l << 6)];
        } else if (h == 2) {           // remap B -> A
            #pragma unroll
            for (int l = 0; l < 16; ++l) st[bB + (l << 6)] = a[l];
            __syncthreads();
            #pragma unroll
            for (int l = 0; l < 16; ++l) a[l] = st[t + (l << 10)];
        }
    }
    // (CZ after layer 3 dropped: |psi|^2 invariant)

    // ---- fused probability reduction (view B) ----
    float SU, Q10, Q11, Q12, Q13;
    {
        SU = Q10 = Q11 = Q12 = Q13 = 0.f;
        #pragma unroll
        for (int l = 0; l < 16; ++l) {
            float p = a[l].x*a[l].x + a[l].y*a[l].y;
            SU  += p;
            Q10 += (l & 8) ? -p : p;    // q10 <-> e3 = l3
            Q11 += (l & 4) ? -p : p;
            Q12 += (l & 2) ? -p : p;
            Q13 += (l & 1) ? -p : p;
        }
    }

    // ---- stage 6: reduce to 14 expectations, layernorm ----
    // View-B sign bit (thread-uniform) for wire ww in 0..9:
    // q0:t9 q1:t8 q2:t7 q3:t6 q4:t3 q5:t1 q6:t5 q7:t0 q8:t4 q9:t2.
    {
        const int lane = t & 63, wv = t >> 6;
        const int sbit[10] = {9, 8, 7, 6, 3, 1, 5, 0, 4, 2};
        #pragma unroll
        for (int ww = 0; ww < NQ; ++ww) {
            float v;
            if      (ww == 10) v = Q10;
            else if (ww == 11) v = Q11;
            else if (ww == 12) v = Q12;
            else if (ww == 13) v = Q13;
            else               v = ((t >> sbit[ww]) & 1) ? -SU : SU;
            #pragma unroll
            for (int off = 32; off > 0; off >>= 1) v += __shfl_down(v, off, 64);
            if (lane == 0) wred[wv][ww] = v;
        }
    }
    __syncthreads();
    if (t < NQ) {
        float s = 0.f;
        #pragma unroll
        for (int k = 0; k < 16; ++k) s += wred[k][t];
        lat[t] = s;
    }
    __syncthreads();
    if (t < NQ) {
        float mu = 0.f;
        #pragma unroll
        for (int k = 0; k < NQ; ++k) mu += lat[k];
        mu *= (1.0f / NQ);
        float var = 0.f;
        #pragma unroll
        for (int k = 0; k < NQ; ++k) { float dv = lat[k] - mu; var += dv*dv; }
        var *= (1.0f / NQ);
        out[b*NQ + t] = (lat[t] - mu) * rsqrtf(var + 1e-5f);
    }
}

extern "C" void kernel_launch(void* const* d_in, const int* in_sizes, int n_in,
                              void* d_out, int out_size, void* d_ws, size_t ws_size,
                              hipStream_t stream)
{
    (void)n_in; (void)d_ws; (void)ws_size; (void)out_size;
    const float* cond = (const float*)d_in[0];
    const float* Wenc = (const float*)d_in[1];
    const float* benc = (const float*)d_in[2];
    const float* wts  = (const float*)d_in[3];
    float* out = (float*)d_out;
    const int B = in_sizes[0] / NQ;   // 256
    qlg_kernel<<<dim3(B), dim3(1024), 0, stream>>>(cond, Wenc, benc, wts, out);
}